// Round 1
// baseline (203.911 us; speedup 1.0000x reference)
//
#include <hip/hip_runtime.h>
#include <hip/hip_bf16.h>

#define E_NUM 64
#define IN_SZ 512
#define OUT_SZ 512
#define N_TOK 131072
#define CAP 3072

#define BM 128
#define BN 128
#define BK 32
#define THREADS 256
#define RT_MAX 24   // CAP/BM
#define CT_NUM 4    // OUT/BN

typedef __attribute__((ext_vector_type(8))) short short8;
typedef __attribute__((ext_vector_type(4))) float f32x4;

__device__ inline unsigned short f2bf(float f) {
    unsigned int u = __float_as_uint(f);
    unsigned int r = (u + 0x7FFF + ((u >> 16) & 1)) >> 16;
    return (unsigned short)r;
}

#define GLOAD_LDS16(g, l)                                                     \
    __builtin_amdgcn_global_load_lds(                                         \
        (const __attribute__((address_space(1))) void*)(g),                   \
        (__attribute__((address_space(3))) void*)(l), 16, 0, 0)

// ---------------- kernel 1: exclusive prefix sum of expert sizes ----------
__global__ void offsets_kernel(const int* __restrict__ sizes, int* __restrict__ offs) {
    int e = threadIdx.x;
    int s = 0;
    for (int i = 0; i < e; ++i) s += sizes[i];
    offs[e] = s;
}

// ---------------- kernel 2: W [E][K][N] f32 -> WT [E][N][K] bf16 ----------
__global__ __launch_bounds__(256) void prep_wt(const float* __restrict__ W,
                                               unsigned short* __restrict__ WT) {
    __shared__ float t[32][33];
    int k0 = blockIdx.x * 32, n0 = blockIdx.y * 32, e = blockIdx.z;
    const float* We = W + (size_t)e * IN_SZ * OUT_SZ;
    int tid = threadIdx.x;
    int r = tid >> 3, c4 = (tid & 7) * 4;
    float4 v = *(const float4*)(We + (size_t)(k0 + r) * OUT_SZ + n0 + c4);
    t[r][c4 + 0] = v.x; t[r][c4 + 1] = v.y; t[r][c4 + 2] = v.z; t[r][c4 + 3] = v.w;
    __syncthreads();
    ushort4 o;
    o.x = f2bf(t[c4 + 0][r]);
    o.y = f2bf(t[c4 + 1][r]);
    o.z = f2bf(t[c4 + 2][r]);
    o.w = f2bf(t[c4 + 3][r]);
    unsigned short* O = WT + (size_t)e * IN_SZ * OUT_SZ + (size_t)(n0 + r) * IN_SZ + k0 + c4;
    *(ushort4*)O = o;
}

// ---------------- kernel 3: grouped GEMM, bf16 MFMA -----------------------
__global__ __launch_bounds__(THREADS, 2) void gemm_moe(
    const float* __restrict__ A, const int* __restrict__ sizes,
    const unsigned short* __restrict__ WT, const int* __restrict__ offs,
    float* __restrict__ out)
{
    // bijective XCD swizzle: 6144 blocks, 768 per XCD chunk
    int b0 = blockIdx.x;
    int wg = (b0 & 7) * 768 + (b0 >> 3);
    int ct = wg & 3;
    int rt = (wg >> 2) % RT_MAX;
    int e  = wg / (RT_MAX * CT_NUM);

    int size_e = sizes[e];
    int rows0 = rt * BM;
    if (rows0 >= size_e) return;
    int off_e = offs[e];
    int rows_rem = size_e - rows0;                      // >= 1
    int maxr = (rows_rem < BM ? rows_rem : BM) - 1;

    __shared__ unsigned short lsA[2][BM * BK];
    __shared__ unsigned short lsB[2][BN * BK];

    int tid = threadIdx.x, l = tid & 63, w = tid >> 6;
    const char* WTe = (const char*)(WT + (size_t)e * IN_SZ * OUT_SZ);
    const float* Abase = A + (size_t)(off_e + rows0) * IN_SZ;

    float4 ar[4];

    auto loadA = [&](int kt) {
        #pragma unroll
        for (int i = 0; i < 4; ++i) {
            int idx = tid + THREADS * i;       // 0..1023 float4 units of the tile
            int row = idx >> 3, c4 = idx & 7;
            int gr = row <= maxr ? row : maxr;
            ar[i] = *(const float4*)(Abase + (size_t)gr * IN_SZ + kt * BK + c4 * 4);
        }
    };
    auto writeA = [&](int buf) {
        #pragma unroll
        for (int i = 0; i < 4; ++i) {
            int idx = tid + THREADS * i;
            ushort4 p;
            p.x = f2bf(ar[i].x); p.y = f2bf(ar[i].y);
            p.z = f2bf(ar[i].z); p.w = f2bf(ar[i].w);
            *(ushort4*)&lsA[buf][idx * 4] = p;
        }
    };
    auto stageB = [&](int buf, int kt) {
        #pragma unroll
        for (int i = 0; i < 2; ++i) {
            int j = (w * 2 + i) * 1024 + l * 16;   // byte offset within 8KB tile
            int n = j >> 6, koff = j & 63;         // 64 bytes per n-row (32 bf16)
            const char* g = WTe + (size_t)(ct * BN + n) * (IN_SZ * 2) + kt * 64 + koff;
            GLOAD_LDS16(g, &lsB[buf][(w * 2 + i) * 512]);
        }
    };

    // prologue
    loadA(0);
    stageB(0, 0);
    writeA(0);
    __syncthreads();

    f32x4 acc[4][4] = {};
    int wm = (w >> 1) * 64, wn = (w & 1) * 64;
    int lrow = l & 15, lk = (l >> 4) * 8;

    for (int kt = 0; kt < IN_SZ / BK; ++kt) {
        int cur = kt & 1;
        if (kt < IN_SZ / BK - 1) {
            loadA(kt + 1);          // global->regs (async)
            stageB(cur ^ 1, kt + 1); // global->LDS  (async)
        }
        short8 af[4], bfr[4];
        #pragma unroll
        for (int m = 0; m < 4; ++m)
            af[m] = *(const short8*)&lsA[cur][(wm + m * 16 + lrow) * BK + lk];
        #pragma unroll
        for (int n = 0; n < 4; ++n)
            bfr[n] = *(const short8*)&lsB[cur][(wn + n * 16 + lrow) * BK + lk];
        #pragma unroll
        for (int m = 0; m < 4; ++m)
            #pragma unroll
            for (int n = 0; n < 4; ++n)
                acc[m][n] = __builtin_amdgcn_mfma_f32_16x16x32_bf16(af[m], bfr[n], acc[m][n], 0, 0, 0);
        if (kt < IN_SZ / BK - 1)
            writeA(cur ^ 1);        // cvt + ds_write (compiler inserts vmcnt wait)
        __syncthreads();
    }

    // epilogue: C/D layout col = lane&15, row = (lane>>4)*4 + reg
    float* outb = out + (size_t)(off_e + rows0) * OUT_SZ + ct * BN + wn;
    #pragma unroll
    for (int m = 0; m < 4; ++m) {
        #pragma unroll
        for (int j = 0; j < 4; ++j) {
            int rl = wm + m * 16 + (l >> 4) * 4 + j;
            if (rl < rows_rem) {
                float* po = outb + (size_t)rl * OUT_SZ + (l & 15);
                #pragma unroll
                for (int n = 0; n < 4; ++n)
                    po[n * 16] = acc[m][n][j];
            }
        }
    }
}

extern "C" void kernel_launch(void* const* d_in, const int* in_sizes, int n_in,
                              void* d_out, int out_size, void* d_ws, size_t ws_size,
                              hipStream_t stream) {
    const float* A      = (const float*)d_in[0];
    const int* sizes    = (const int*)d_in[1];
    const float* W      = (const float*)d_in[2];
    float* out          = (float*)d_out;

    unsigned short* WT  = (unsigned short*)d_ws;                       // 32 MB
    int* offs           = (int*)((char*)d_ws + (size_t)E_NUM * IN_SZ * OUT_SZ * 2);

    offsets_kernel<<<1, E_NUM, 0, stream>>>(sizes, offs);
    prep_wt<<<dim3(IN_SZ / 32, OUT_SZ / 32, E_NUM), 256, 0, stream>>>(W, WT);
    gemm_moe<<<E_NUM * RT_MAX * CT_NUM, THREADS, 0, stream>>>(A, sizes, WT, offs, out);
}

// Round 2
// 197.717 us; speedup vs baseline: 1.0313x; 1.0313x over previous
//
#include <hip/hip_runtime.h>
#include <hip/hip_bf16.h>

#define E_NUM 64
#define IN_SZ 512
#define OUT_SZ 512
#define N_TOK 131072
#define CAP 3072

#define BM 128
#define BN 256
#define BK 32
#define THREADS 256
#define RT_MAX 24   // CAP/BM
#define CT_NUM 2    // OUT/BN

typedef __attribute__((ext_vector_type(8))) short short8;
typedef __attribute__((ext_vector_type(4))) float f32x4;

__device__ inline unsigned short f2bf(float f) {
    unsigned int u = __float_as_uint(f);
    unsigned int r = (u + 0x7FFF + ((u >> 16) & 1)) >> 16;
    return (unsigned short)r;
}

#define GLOAD_LDS16(g, l)                                                     \
    __builtin_amdgcn_global_load_lds(                                         \
        (const __attribute__((address_space(1))) void*)(g),                   \
        (__attribute__((address_space(3))) void*)(l), 16, 0, 0)

// ---------------- kernel 1: exclusive prefix sum of expert sizes ----------
__global__ void offsets_kernel(const int* __restrict__ sizes, int* __restrict__ offs) {
    int e = threadIdx.x;
    int s = 0;
    for (int i = 0; i < e; ++i) s += sizes[i];
    offs[e] = s;
}

// ---------------- kernel 2: W [E][K][N] f32 -> WT [E][N][K] bf16 ----------
__global__ __launch_bounds__(256) void prep_wt(const float* __restrict__ W,
                                               unsigned short* __restrict__ WT) {
    __shared__ float t[32][33];
    int k0 = blockIdx.x * 32, n0 = blockIdx.y * 32, e = blockIdx.z;
    const float* We = W + (size_t)e * IN_SZ * OUT_SZ;
    int tid = threadIdx.x;
    int r = tid >> 3, c4 = (tid & 7) * 4;
    float4 v = *(const float4*)(We + (size_t)(k0 + r) * OUT_SZ + n0 + c4);
    t[r][c4 + 0] = v.x; t[r][c4 + 1] = v.y; t[r][c4 + 2] = v.z; t[r][c4 + 3] = v.w;
    __syncthreads();
    ushort4 o;
    o.x = f2bf(t[c4 + 0][r]);
    o.y = f2bf(t[c4 + 1][r]);
    o.z = f2bf(t[c4 + 2][r]);
    o.w = f2bf(t[c4 + 3][r]);
    unsigned short* O = WT + (size_t)e * IN_SZ * OUT_SZ + (size_t)(n0 + r) * IN_SZ + k0 + c4;
    *(ushort4*)O = o;
}

// ---------------- kernel 3: grouped GEMM, bf16 MFMA -----------------------
// LDS swizzle: within each 64B row (BK=32 bf16), col_byte ^= ((row>>1)&3)<<4.
// A side: applied at ds_write (reg-staged) and ds_read.
// B side: global_load_lds writes linearly -> pre-swizzle the GLOBAL source
// address; ds_read applies the same XOR (both-sides involution, rule #21).
__global__ __launch_bounds__(THREADS, 2) void gemm_moe(
    const float* __restrict__ A, const int* __restrict__ sizes,
    const unsigned short* __restrict__ WT, const int* __restrict__ offs,
    float* __restrict__ out)
{
    // bijective XCD swizzle: 3072 blocks, 384 per XCD chunk
    int b0 = blockIdx.x;
    int wg = (b0 & 7) * (E_NUM * RT_MAX * CT_NUM / 8) + (b0 >> 3);
    int ct = wg & (CT_NUM - 1);
    int rt = (wg >> 1) % RT_MAX;
    int e  = wg / (RT_MAX * CT_NUM);

    int size_e = sizes[e];
    int rows0 = rt * BM;
    if (rows0 >= size_e) return;
    int off_e = offs[e];
    int rows_rem = size_e - rows0;                      // >= 1
    int maxr = (rows_rem < BM ? rows_rem : BM) - 1;

    __shared__ unsigned short lsA[2][BM * BK];   // 16 KB
    __shared__ unsigned short lsB[2][BN * BK];   // 32 KB

    int tid = threadIdx.x, l = tid & 63, w = tid >> 6;
    const char* WTe = (const char*)(WT + (size_t)e * IN_SZ * OUT_SZ);
    const float* Abase = A + (size_t)(off_e + rows0) * IN_SZ;

    float4 ar[4];

    auto loadA = [&](int kt) {
        #pragma unroll
        for (int i = 0; i < 4; ++i) {
            int idx = tid + THREADS * i;       // 0..1023 float4 units of the tile
            int row = idx >> 3, c4 = idx & 7;
            int gr = row <= maxr ? row : maxr;
            ar[i] = *(const float4*)(Abase + (size_t)gr * IN_SZ + kt * BK + c4 * 4);
        }
    };
    auto writeA = [&](int buf) {
        #pragma unroll
        for (int i = 0; i < 4; ++i) {
            int idx = tid + THREADS * i;
            int row = idx >> 3, cb = (idx & 7) * 8;
            int cbs = cb ^ ((((row >> 1) & 3)) << 4);
            ushort4 p;
            p.x = f2bf(ar[i].x); p.y = f2bf(ar[i].y);
            p.z = f2bf(ar[i].z); p.w = f2bf(ar[i].w);
            *(ushort4*)((char*)&lsA[buf][0] + row * 64 + cbs) = p;
        }
    };
    auto stageB = [&](int buf, int kt) {
        #pragma unroll
        for (int i = 0; i < 4; ++i) {
            int j = (w * 4 + i) * 1024 + l * 16;   // linear byte offset in 16KB tile
            int n = j >> 6, c = j & 63;            // 64 bytes per n-row
            int csrc = c ^ ((((n >> 1) & 3)) << 4);
            const char* g = WTe + (size_t)(ct * BN + n) * (IN_SZ * 2) + kt * 64 + csrc;
            GLOAD_LDS16(g, &lsB[buf][(w * 4 + i) * 512]);
        }
    };

    // prologue
    loadA(0);
    stageB(0, 0);
    writeA(0);
    __syncthreads();

    f32x4 acc[4][8] = {};
    int wm = (w >> 1) * 64, wn = (w & 1) * 128;
    int lrow = l & 15;
    int cb = ((l >> 4) * 16) ^ ((((lrow >> 1) & 3)) << 4);

    for (int kt = 0; kt < IN_SZ / BK; ++kt) {
        int cur = kt & 1;
        if (kt < IN_SZ / BK - 1) {
            loadA(kt + 1);           // global->regs (async)
            stageB(cur ^ 1, kt + 1); // global->LDS  (async)
        }
        const char* pA = (const char*)&lsA[cur][0];
        const char* pB = (const char*)&lsB[cur][0];
        short8 af[4];
        #pragma unroll
        for (int m = 0; m < 4; ++m)
            af[m] = *(const short8*)(pA + (wm + m * 16 + lrow) * 64 + cb);
        #pragma unroll
        for (int nh = 0; nh < 2; ++nh) {
            short8 bfr[4];
            #pragma unroll
            for (int n2 = 0; n2 < 4; ++n2)
                bfr[n2] = *(const short8*)(pB + (wn + nh * 64 + n2 * 16 + lrow) * 64 + cb);
            #pragma unroll
            for (int m = 0; m < 4; ++m)
                #pragma unroll
                for (int n2 = 0; n2 < 4; ++n2)
                    acc[m][nh * 4 + n2] = __builtin_amdgcn_mfma_f32_16x16x32_bf16(
                        af[m], bfr[n2], acc[m][nh * 4 + n2], 0, 0, 0);
        }
        if (kt < IN_SZ / BK - 1)
            writeA(cur ^ 1);        // cvt + ds_write (compiler inserts vmcnt wait)
        __syncthreads();
    }

    // epilogue: C/D layout col = lane&15, row = (lane>>4)*4 + reg
    float* outb = out + (size_t)(off_e + rows0) * OUT_SZ + ct * BN + wn;
    #pragma unroll
    for (int m = 0; m < 4; ++m) {
        #pragma unroll
        for (int j = 0; j < 4; ++j) {
            int rl = wm + m * 16 + (l >> 4) * 4 + j;
            if (rl < rows_rem) {
                float* po = outb + (size_t)rl * OUT_SZ + (l & 15);
                #pragma unroll
                for (int n = 0; n < 8; ++n)
                    po[n * 16] = acc[m][n][j];
            }
        }
    }
}

extern "C" void kernel_launch(void* const* d_in, const int* in_sizes, int n_in,
                              void* d_out, int out_size, void* d_ws, size_t ws_size,
                              hipStream_t stream) {
    const float* A      = (const float*)d_in[0];
    const int* sizes    = (const int*)d_in[1];
    const float* W      = (const float*)d_in[2];
    float* out          = (float*)d_out;

    unsigned short* WT  = (unsigned short*)d_ws;                       // 32 MB
    int* offs           = (int*)((char*)d_ws + (size_t)E_NUM * IN_SZ * OUT_SZ * 2);

    offsets_kernel<<<1, E_NUM, 0, stream>>>(sizes, offs);
    prep_wt<<<dim3(IN_SZ / 32, OUT_SZ / 32, E_NUM), 256, 0, stream>>>(W, WT);
    gemm_moe<<<E_NUM * RT_MAX * CT_NUM, THREADS, 0, stream>>>(A, sizes, WT, offs, out);
}